// Round 4
// baseline (2617.120 us; speedup 1.0000x reference)
//
#include <hip/hip_runtime.h>

#define B_ 8
#define N_ 8192
#define S_ 1024
#define NS_ 64

// out layout (floats) — also used as staging (fully rewritten every launch)
#define OUT0 0                 // new_xyz (B,3,1024)
#define OUT1 24576             // new_points (B,128,1024); rows 0..63 of each
                               //   column hold gi int-bits between kernels 3&4
#define OUT2 1073152           // new_seed (B,1024); holds fps int-bits between
                               //   kernels 1&2

// ---------------------------------------------------------------------------
// Kernel 1: farthest point sampling. One block per batch, 1024 sequential
// steps, ONE barrier per step. Per-thread argmax fused into the dist update
// (strict > keeps lowest index = numpy first-occurrence argmax); winner's
// coords ride along the reduction so no owner-push is needed. Wave reduce on
// packed u64 (dist_bits<<32 | 8191-idx); cross-wave via double-buffered LDS
// slots + redundant 16-way shuffle reduce. Distance arithmetic in the
// reference's exact f32 op order (contract off) -> new_seed bit-exact.
// ---------------------------------------------------------------------------
#define FPS_T 1024
#define FPS_J 8

__global__ __launch_bounds__(1024) void fps_kernel(const float* __restrict__ xyz,
                                                   float* out) {
    const int b = blockIdx.x;
    const int t = threadIdx.x;          // 0..1023
    const int lane = t & 63;
    const int wid = t >> 6;             // 0..15
    const float* X = xyz + b * 3 * N_;

    float px[FPS_J], py[FPS_J], pz[FPS_J], dist[FPS_J];
#pragma unroll
    for (int j = 0; j < FPS_J; ++j) {
        int n = t + FPS_T * j;
        px[j] = X[n];
        py[j] = X[N_ + n];
        pz[j] = X[2 * N_ + n];
        dist[j] = 1e10f;
    }

    __shared__ unsigned long long pvp[2][16];
    __shared__ float4 pxyz[2][16];

    float* oseed = out + OUT2 + b * S_;

    // initial centroid = index 0; everyone broadcast-loads its coords (L1/L2)
    int ci = 0;
    float c0 = X[0], c1 = X[N_], c2 = X[2 * N_];

    for (int step = 0; step < S_; ++step) {
        if (t == 0) oseed[step] = __int_as_float(ci);
        const int bsel = step & 1;

        // per-thread dist update + fused argmax (value, neg-index, coords)
        float mval = -1.0f, mx = 0.f, my = 0.f, mz = 0.f;
        int mneg = 0;
        {
#pragma clang fp contract(off)
#pragma unroll
            for (int j = 0; j < FPS_J; ++j) {
                float e0 = px[j] - c0;
                float e1 = py[j] - c1;
                float e2 = pz[j] - c2;
                float d = (e0 * e0 + e1 * e1) + e2 * e2;
                float dm = fminf(dist[j], d);
                dist[j] = dm;
                bool gt = dm > mval;
                mval = gt ? dm : mval;
                mneg = gt ? (8191 - (t + FPS_T * j)) : mneg;
                mx = gt ? px[j] : mx;
                my = gt ? py[j] : my;
                mz = gt ? pz[j] : mz;
            }
        }

        // stage 1: wave xor-reduce on packed (dist_bits, 8191-idx)
        unsigned long long pair =
            ((unsigned long long)__float_as_uint(mval) << 32) | (unsigned)mneg;
#pragma unroll
        for (int off = 1; off < 64; off <<= 1) {
            unsigned long long op = __shfl_xor(pair, off, 64);
            float ox = __shfl_xor(mx, off, 64);
            float oy = __shfl_xor(my, off, 64);
            float oz = __shfl_xor(mz, off, 64);
            bool take = op > pair;
            pair = take ? op : pair;
            mx = take ? ox : mx;
            my = take ? oy : my;
            mz = take ? oz : mz;
        }
        if (lane == 0) {
            pvp[bsel][wid] = pair;
            pxyz[bsel][wid] = make_float4(mx, my, mz, 0.f);
        }
        __syncthreads();   // the ONE barrier per step

        // stage 2: redundant reduce over the 16 wave winners
        int w = lane & 15;
        unsigned long long p2 = pvp[bsel][w];
#pragma unroll
        for (int off = 1; off < 16; off <<= 1) {
            unsigned long long op = __shfl_xor(p2, off, 64);
            int ow = __shfl_xor(w, off, 64);
            bool take = op > p2;
            p2 = take ? op : p2;
            w = take ? ow : w;
        }
        float4 c = pxyz[bsel][w];
        c0 = c.x; c1 = c.y; c2 = c.z;
        ci = 8191 - (int)(unsigned)(p2 & 0xffffffffull);
    }
}

// ---------------------------------------------------------------------------
// Kernel 2: read fps int-bits from OUT2, gather centroid coords -> OUT0,
// overwrite OUT2 with the gathered seed value (same-thread read-then-write).
// ---------------------------------------------------------------------------
__global__ __launch_bounds__(256) void gather_kernel(const float* __restrict__ xyz,
                                                     const int* __restrict__ seed,
                                                     float* out) {
    int t = blockIdx.x * 256 + threadIdx.x;   // 8192
    int b = t >> 10, s = t & 1023;
    int idx = __float_as_int(out[OUT2 + t]) & 8191;
    const float* X = xyz + b * 3 * N_;
    float x = X[idx], y = X[N_ + idx], z = X[2 * N_ + idx];
    out[OUT0 + (b * 3 + 0) * S_ + s] = x;
    out[OUT0 + (b * 3 + 1) * S_ + s] = y;
    out[OUT0 + (b * 3 + 2) * S_ + s] = z;
    out[OUT2 + t] = (float)seed[b * N_ + idx];
}

// ---------------------------------------------------------------------------
// Kernel 3: ball query. One wave per centroid; ballot-compaction collects the
// 64 lowest-index in-radius points; pad with first. |c|^2 and |x|^2
// recomputed inline in the reference op order; result indices stored as
// int-bits in rows 0..63 of this centroid's own OUT1 column.
// ---------------------------------------------------------------------------
__global__ __launch_bounds__(256) void ballquery_kernel(const float* __restrict__ xyz,
                                                        float* out) {
    int wid = threadIdx.x >> 6, lane = threadIdx.x & 63;
    int sg = blockIdx.x * 4 + wid;            // 0..8191 centroid id
    int b = sg >> 10, s = sg & 1023;
    const float* X = xyz + b * 3 * N_;
    float c0 = out[OUT0 + (b * 3 + 0) * S_ + s];
    float c1 = out[OUT0 + (b * 3 + 1) * S_ + s];
    float c2 = out[OUT0 + (b * 3 + 2) * S_ + s];
    float ss;
    {
#pragma clang fp contract(off)
        ss = (c0 * c0 + c1 * c1) + c2 * c2;
    }
    float* G = out + OUT1 + (b * 128) * S_ + s;   // column s, rows 0..63, stride S_

    int cnt = 0, first = 0;
    for (int base = 0; base < N_ && cnt < NS_; base += 64) {
        int n = base + lane;
        float x = X[n], y = X[N_ + n], z = X[2 * N_ + n];
        float d;
        {
#pragma clang fp contract(off)
            float ds = (x * x + y * y) + z * z;
            float dot = (x * c0 + y * c1) + z * c2;
            d = ((-2.0f * dot) + ss) + ds;
        }
        bool inr = (d <= 0.04f);
        unsigned long long mask = __ballot(inr);
        if (mask) {
            if (cnt == 0) first = base + __ffsll((unsigned long long)mask) - 1;
            int pos = cnt + (int)__popcll(mask & ((1ull << lane) - 1ull));
            if (inr && pos < NS_) G[pos * S_] = __int_as_float(n);
            cnt += (int)__popcll(mask);
        }
    }
    if (lane >= cnt && lane < NS_) G[lane * S_] = __int_as_float(first);
}

// ---------------------------------------------------------------------------
// Kernel 4: fused gather + 3-layer pointwise MLP (+BN+ReLU) + max over K.
// One block (256 thr) per centroid. k = lane (64 rows), wave wq owns an
// o-slice. Reads gi int-bits from its own OUT1 column, then overwrites that
// column with the final features (read happens before first barrier; writes
// at the end — same block only, race-free).
// ---------------------------------------------------------------------------
__global__ __launch_bounds__(256) void mlp_kernel(
    const float* __restrict__ xyz, const float* __restrict__ pts,
    const float* __restrict__ w0, const float* __restrict__ b0,
    const float* __restrict__ g0, const float* __restrict__ be0,
    const float* __restrict__ m0, const float* __restrict__ v0,
    const float* __restrict__ w1, const float* __restrict__ b1,
    const float* __restrict__ g1, const float* __restrict__ be1,
    const float* __restrict__ m1, const float* __restrict__ v1,
    const float* __restrict__ w2, const float* __restrict__ b2,
    const float* __restrict__ g2, const float* __restrict__ be2,
    const float* __restrict__ m2, const float* __restrict__ v2,
    float* out) {
    const int sg = blockIdx.x;
    const int b = sg >> 10, s = sg & 1023;
    const int t = threadIdx.x;
    const int lane = t & 63;
    const int wq = __builtin_amdgcn_readfirstlane(t >> 6);

    __shared__ float f0[64 * 9];
    __shared__ float bufA[64 * 65];
    __shared__ float bufB[64 * 65];

    if (t < 64) {
        int gidx = __float_as_int(out[OUT1 + (b * 128 + t) * S_ + s]) & 8191;
        const float* X = xyz + b * 3 * N_;
        const float* P = pts + b * 3 * N_;
        float cx = out[OUT0 + (b * 3 + 0) * S_ + s];
        float cy = out[OUT0 + (b * 3 + 1) * S_ + s];
        float cz = out[OUT0 + (b * 3 + 2) * S_ + s];
        f0[t * 9 + 0] = X[gidx] - cx;
        f0[t * 9 + 1] = X[N_ + gidx] - cy;
        f0[t * 9 + 2] = X[2 * N_ + gidx] - cz;
        f0[t * 9 + 3] = P[gidx];
        f0[t * 9 + 4] = P[N_ + gidx];
        f0[t * 9 + 5] = P[2 * N_ + gidx];
    }
    __syncthreads();

    // layer 0: 6 -> 64
    {
        float in[6];
#pragma unroll
        for (int c = 0; c < 6; ++c) in[c] = f0[lane * 9 + c];
#pragma unroll 1
        for (int i = 0; i < 16; ++i) {
            int o = wq * 16 + i;
            float acc = 0.0f;
#pragma unroll
            for (int c = 0; c < 6; ++c) acc = fmaf(in[c], w0[o * 6 + c], acc);
            float sc = g0[o] / sqrtf(v0[o] + 1e-5f);
            float y = (acc + b0[o] - m0[o]) * sc + be0[o];
            bufA[lane * 65 + o] = fmaxf(y, 0.0f);
        }
    }
    __syncthreads();

    // layer 1: 64 -> 64
    {
        float r[64];
#pragma unroll
        for (int c = 0; c < 64; ++c) r[c] = bufA[lane * 65 + c];
#pragma unroll 1
        for (int i = 0; i < 16; ++i) {
            int o = wq * 16 + i;
            float acc = 0.0f;
#pragma unroll
            for (int c = 0; c < 64; ++c) acc = fmaf(r[c], w1[o * 64 + c], acc);
            float sc = g1[o] / sqrtf(v1[o] + 1e-5f);
            float y = (acc + b1[o] - m1[o]) * sc + be1[o];
            bufB[lane * 65 + o] = fmaxf(y, 0.0f);
        }
    }
    __syncthreads();

    // layer 2: 64 -> 128, fused BN+ReLU+max over k (k = lane -> wave reduce)
    {
        float r[64];
#pragma unroll
        for (int c = 0; c < 64; ++c) r[c] = bufB[lane * 65 + c];
#pragma unroll 1
        for (int i = 0; i < 32; ++i) {
            int o = wq * 32 + i;
            float acc = 0.0f;
#pragma unroll
            for (int c = 0; c < 64; ++c) acc = fmaf(r[c], w2[o * 64 + c], acc);
            float sc = g2[o] / sqrtf(v2[o] + 1e-5f);
            float y = (acc + b2[o] - m2[o]) * sc + be2[o];
            y = fmaxf(y, 0.0f);
#pragma unroll
            for (int off = 1; off < 64; off <<= 1)
                y = fmaxf(y, __shfl_xor(y, off, 64));
            if (lane == 0) out[OUT1 + (b * 128 + o) * S_ + s] = y;
        }
    }
}

extern "C" void kernel_launch(void* const* d_in, const int* in_sizes, int n_in,
                              void* d_out, int out_size, void* d_ws, size_t ws_size,
                              hipStream_t stream) {
    const float* xyz  = (const float*)d_in[0];
    const float* pts  = (const float*)d_in[1];
    const int*   seed = (const int*)d_in[2];
    const float* w0 = (const float*)d_in[3];
    const float* b0 = (const float*)d_in[4];
    const float* g0 = (const float*)d_in[5];
    const float* be0 = (const float*)d_in[6];
    const float* m0 = (const float*)d_in[7];
    const float* v0 = (const float*)d_in[8];
    const float* w1 = (const float*)d_in[9];
    const float* b1 = (const float*)d_in[10];
    const float* g1 = (const float*)d_in[11];
    const float* be1 = (const float*)d_in[12];
    const float* m1 = (const float*)d_in[13];
    const float* v1 = (const float*)d_in[14];
    const float* w2 = (const float*)d_in[15];
    const float* b2 = (const float*)d_in[16];
    const float* g2 = (const float*)d_in[17];
    const float* be2 = (const float*)d_in[18];
    const float* m2 = (const float*)d_in[19];
    const float* v2 = (const float*)d_in[20];
    float* out = (float*)d_out;
    (void)d_ws; (void)ws_size;   // workspace intentionally unused

    fps_kernel<<<dim3(B_), dim3(FPS_T), 0, stream>>>(xyz, out);
    gather_kernel<<<dim3(8192 / 256), dim3(256), 0, stream>>>(xyz, seed, out);
    ballquery_kernel<<<dim3(2048), dim3(256), 0, stream>>>(xyz, out);
    mlp_kernel<<<dim3(8192), dim3(256), 0, stream>>>(xyz, pts,
        w0, b0, g0, be0, m0, v0,
        w1, b1, g1, be1, m1, v1,
        w2, b2, g2, be2, m2, v2,
        out);
}

// Round 6
// 1662.472 us; speedup vs baseline: 1.5742x; 1.5742x over previous
//
#include <hip/hip_runtime.h>

#define B_ 8
#define N_ 8192
#define S_ 1024
#define NS_ 64

typedef float v2f __attribute__((ext_vector_type(2)));

// out layout (floats) — also used as staging (fully rewritten every launch)
#define OUT0 0                 // new_xyz (B,3,1024)
#define OUT1 24576             // new_points (B,128,1024); rows 0..63 of each
                               //   column hold gi int-bits between kernels 3&4
#define OUT2 1073152           // new_seed (B,1024); holds fps int-bits between
                               //   kernels 1&2

// ---------------------------------------------------------------------------
// DPP full-wave (64-lane) f32 max: row_shr 1/2/4/8 then row_bcast 15/31.
// Result valid in lane 63; broadcast via readlane. CTRL must be a
// compile-time constant -> template parameter.
// ---------------------------------------------------------------------------
template <int CTRL>
static __device__ __forceinline__ float dpp_max_step(float v) {
    int o = __builtin_amdgcn_update_dpp(__float_as_int(v), __float_as_int(v),
                                        CTRL, 0xf, 0xf, false);
    return fmaxf(v, __int_as_float(o));
}
static __device__ __forceinline__ float wave_max_f32(float v) {
    v = dpp_max_step<0x111>(v);   // row_shr:1
    v = dpp_max_step<0x112>(v);   // row_shr:2
    v = dpp_max_step<0x114>(v);   // row_shr:4
    v = dpp_max_step<0x118>(v);   // row_shr:8  -> lane 15 of each row = row max
    v = dpp_max_step<0x142>(v);   // row_bcast:15
    v = dpp_max_step<0x143>(v);   // row_bcast:31 -> lane 63 = wave max
    return __int_as_float(__builtin_amdgcn_readlane(__float_as_int(v), 63));
}

// ---------------------------------------------------------------------------
// Kernel 1: farthest point sampling. One block per batch, 256 threads
// (4 waves, 1/SIMD), 32 pts/thread as 16 float2 (compiler emits v_pk_* —
// IEEE-identical to scalar, so argmax matches numpy bit-exactly).
// Per step: packed dist update + value max -> DPP wave max -> LDS (4 slots)
// -> bar1 -> gw = max of 4 -> mask rescan (cmp/or/ffs) -> LDS atomicMin
// (lowest index = numpy first-occurrence) -> bar2 -> uniform coord fetch.
// amin double-buffered: t0 resets the other buffer between bar1/bar2.
// ---------------------------------------------------------------------------
__global__ __launch_bounds__(256, 1) void fps_kernel(const float* __restrict__ xyz,
                                                     float* out) {
    const int b = blockIdx.x;
    const int t = threadIdx.x;          // 0..255
    const int lane = t & 63;
    const int wid = t >> 6;             // 0..3
    const float* X = xyz + b * 3 * N_;

    // pair j components: n = t + 512*j (x), t + 512*j + 256 (y)
    v2f px2[16], py2[16], pz2[16], dist2[16];
#pragma unroll
    for (int j = 0; j < 16; ++j) {
        int n = t + 512 * j;
        px2[j] = (v2f){X[n], X[n + 256]};
        py2[j] = (v2f){X[N_ + n], X[N_ + n + 256]};
        pz2[j] = (v2f){X[2 * N_ + n], X[2 * N_ + n + 256]};
        dist2[j] = (v2f){1e10f, 1e10f};
    }

    __shared__ float pvw[4];
    __shared__ int amin[2];
    if (t == 0) { amin[0] = 0x7fffffff; amin[1] = 0x7fffffff; }
    __syncthreads();

    float* oseed = out + OUT2 + b * S_;

    int ci = 0;
    float c0 = X[0], c1 = X[N_], c2 = X[2 * N_];

    for (int step = 0; step < S_; ++step) {
        if (t == 0) oseed[step] = __int_as_float(ci);
        const int bsel = step & 1;

        // phase 1: packed dist update + value-only max
        v2f mv = (v2f){-1.0f, -1.0f};
        {
#pragma clang fp contract(off)
            v2f c0v = (v2f){c0, c0};
            v2f c1v = (v2f){c1, c1};
            v2f c2v = (v2f){c2, c2};
#pragma unroll
            for (int j = 0; j < 16; ++j) {
                v2f e0 = px2[j] - c0v;
                v2f e1 = py2[j] - c1v;
                v2f e2 = pz2[j] - c2v;
                v2f q0 = e0 * e0;
                v2f q1 = e1 * e1;
                v2f q2 = e2 * e2;
                v2f d  = (q0 + q1) + q2;
                v2f dm = __builtin_elementwise_min(dist2[j], d);
                dist2[j] = dm;
                mv = __builtin_elementwise_max(mv, dm);
            }
        }
        float m = fmaxf(mv.x, mv.y);

        // wave value max via DPP; lane 0 posts to LDS
        float wmax = wave_max_f32(m);
        if (lane == 0) pvw[wid] = wmax;
        __syncthreads();   // bar1

        if (t == 0) amin[1 - bsel] = 0x7fffffff;   // reset OTHER buffer

        float gw = fmaxf(fmaxf(pvw[0], pvw[1]), fmaxf(pvw[2], pvw[3]));

        // rescan: bitmask of local components equal to gw (ascending index)
        unsigned mask = 0u;
#pragma unroll
        for (int j = 0; j < 16; ++j) {
            if (dist2[j].x == gw) mask |= (1u << (2 * j));
            if (dist2[j].y == gw) mask |= (1u << (2 * j + 1));
        }
        if (mask) {
            int bit = __ffs(mask) - 1;
            int idx = t + (bit << 8);
            atomicMin(&amin[bsel], idx);
        }
        __syncthreads();   // bar2

        ci = amin[bsel] & 8191;
        int cu = __builtin_amdgcn_readfirstlane(ci);
        c0 = X[cu];
        c1 = X[N_ + cu];
        c2 = X[2 * N_ + cu];
    }
}

// ---------------------------------------------------------------------------
// Kernel 2: read fps int-bits from OUT2, gather centroid coords -> OUT0,
// overwrite OUT2 with the gathered seed value (same-thread read-then-write).
// ---------------------------------------------------------------------------
__global__ __launch_bounds__(256) void gather_kernel(const float* __restrict__ xyz,
                                                     const int* __restrict__ seed,
                                                     float* out) {
    int t = blockIdx.x * 256 + threadIdx.x;   // 8192
    int b = t >> 10, s = t & 1023;
    int idx = __float_as_int(out[OUT2 + t]) & 8191;
    const float* X = xyz + b * 3 * N_;
    float x = X[idx], y = X[N_ + idx], z = X[2 * N_ + idx];
    out[OUT0 + (b * 3 + 0) * S_ + s] = x;
    out[OUT0 + (b * 3 + 1) * S_ + s] = y;
    out[OUT0 + (b * 3 + 2) * S_ + s] = z;
    out[OUT2 + t] = (float)seed[b * N_ + idx];
}

// ---------------------------------------------------------------------------
// Kernel 3: ball query. One wave per centroid; ballot-compaction collects the
// 64 lowest-index in-radius points; pad with first. |c|^2 and |x|^2
// recomputed inline in the reference op order; result indices stored as
// int-bits in rows 0..63 of this centroid's own OUT1 column.
// ---------------------------------------------------------------------------
__global__ __launch_bounds__(256) void ballquery_kernel(const float* __restrict__ xyz,
                                                        float* out) {
    int wid = threadIdx.x >> 6, lane = threadIdx.x & 63;
    int sg = blockIdx.x * 4 + wid;            // 0..8191 centroid id
    int b = sg >> 10, s = sg & 1023;
    const float* X = xyz + b * 3 * N_;
    float c0 = out[OUT0 + (b * 3 + 0) * S_ + s];
    float c1 = out[OUT0 + (b * 3 + 1) * S_ + s];
    float c2 = out[OUT0 + (b * 3 + 2) * S_ + s];
    float ss;
    {
#pragma clang fp contract(off)
        ss = (c0 * c0 + c1 * c1) + c2 * c2;
    }
    float* G = out + OUT1 + (b * 128) * S_ + s;   // column s, rows 0..63, stride S_

    int cnt = 0, first = 0;
    for (int base = 0; base < N_ && cnt < NS_; base += 64) {
        int n = base + lane;
        float x = X[n], y = X[N_ + n], z = X[2 * N_ + n];
        float d;
        {
#pragma clang fp contract(off)
            float ds = (x * x + y * y) + z * z;
            float dot = (x * c0 + y * c1) + z * c2;
            d = ((-2.0f * dot) + ss) + ds;
        }
        bool inr = (d <= 0.04f);
        unsigned long long mask = __ballot(inr);
        if (mask) {
            if (cnt == 0) first = base + __ffsll((unsigned long long)mask) - 1;
            int pos = cnt + (int)__popcll(mask & ((1ull << lane) - 1ull));
            if (inr && pos < NS_) G[pos * S_] = __int_as_float(n);
            cnt += (int)__popcll(mask);
        }
    }
    if (lane >= cnt && lane < NS_) G[lane * S_] = __int_as_float(first);
}

// ---------------------------------------------------------------------------
// Kernel 4: fused gather + 3-layer pointwise MLP (+BN+ReLU) + max over K.
// One block (256 thr) per centroid. k = lane (64 rows), wave wq owns an
// o-slice. Reads gi int-bits from its own OUT1 column, then overwrites that
// column with the final features (read happens before first barrier; writes
// at the end — same block only, race-free).
// ---------------------------------------------------------------------------
__global__ __launch_bounds__(256) void mlp_kernel(
    const float* __restrict__ xyz, const float* __restrict__ pts,
    const float* __restrict__ w0, const float* __restrict__ b0,
    const float* __restrict__ g0, const float* __restrict__ be0,
    const float* __restrict__ m0, const float* __restrict__ v0,
    const float* __restrict__ w1, const float* __restrict__ b1,
    const float* __restrict__ g1, const float* __restrict__ be1,
    const float* __restrict__ m1, const float* __restrict__ v1,
    const float* __restrict__ w2, const float* __restrict__ b2,
    const float* __restrict__ g2, const float* __restrict__ be2,
    const float* __restrict__ m2, const float* __restrict__ v2,
    float* out) {
    const int sg = blockIdx.x;
    const int b = sg >> 10, s = sg & 1023;
    const int t = threadIdx.x;
    const int lane = t & 63;
    const int wq = __builtin_amdgcn_readfirstlane(t >> 6);

    __shared__ float f0[64 * 9];
    __shared__ float bufA[64 * 65];
    __shared__ float bufB[64 * 65];

    if (t < 64) {
        int gidx = __float_as_int(out[OUT1 + (b * 128 + t) * S_ + s]) & 8191;
        const float* X = xyz + b * 3 * N_;
        const float* P = pts + b * 3 * N_;
        float cx = out[OUT0 + (b * 3 + 0) * S_ + s];
        float cy = out[OUT0 + (b * 3 + 1) * S_ + s];
        float cz = out[OUT0 + (b * 3 + 2) * S_ + s];
        f0[t * 9 + 0] = X[gidx] - cx;
        f0[t * 9 + 1] = X[N_ + gidx] - cy;
        f0[t * 9 + 2] = X[2 * N_ + gidx] - cz;
        f0[t * 9 + 3] = P[gidx];
        f0[t * 9 + 4] = P[N_ + gidx];
        f0[t * 9 + 5] = P[2 * N_ + gidx];
    }
    __syncthreads();

    // layer 0: 6 -> 64
    {
        float in[6];
#pragma unroll
        for (int c = 0; c < 6; ++c) in[c] = f0[lane * 9 + c];
#pragma unroll 1
        for (int i = 0; i < 16; ++i) {
            int o = wq * 16 + i;
            float acc = 0.0f;
#pragma unroll
            for (int c = 0; c < 6; ++c) acc = fmaf(in[c], w0[o * 6 + c], acc);
            float sc = g0[o] / sqrtf(v0[o] + 1e-5f);
            float y = (acc + b0[o] - m0[o]) * sc + be0[o];
            bufA[lane * 65 + o] = fmaxf(y, 0.0f);
        }
    }
    __syncthreads();

    // layer 1: 64 -> 64
    {
        float r[64];
#pragma unroll
        for (int c = 0; c < 64; ++c) r[c] = bufA[lane * 65 + c];
#pragma unroll 1
        for (int i = 0; i < 16; ++i) {
            int o = wq * 16 + i;
            float acc = 0.0f;
#pragma unroll
            for (int c = 0; c < 64; ++c) acc = fmaf(r[c], w1[o * 64 + c], acc);
            float sc = g1[o] / sqrtf(v1[o] + 1e-5f);
            float y = (acc + b1[o] - m1[o]) * sc + be1[o];
            bufB[lane * 65 + o] = fmaxf(y, 0.0f);
        }
    }
    __syncthreads();

    // layer 2: 64 -> 128, fused BN+ReLU+max over k (k = lane -> wave reduce)
    {
        float r[64];
#pragma unroll
        for (int c = 0; c < 64; ++c) r[c] = bufB[lane * 65 + c];
#pragma unroll 1
        for (int i = 0; i < 32; ++i) {
            int o = wq * 32 + i;
            float acc = 0.0f;
#pragma unroll
            for (int c = 0; c < 64; ++c) acc = fmaf(r[c], w2[o * 64 + c], acc);
            float sc = g2[o] / sqrtf(v2[o] + 1e-5f);
            float y = (acc + b2[o] - m2[o]) * sc + be2[o];
            y = fmaxf(y, 0.0f);
#pragma unroll
            for (int off = 1; off < 64; off <<= 1)
                y = fmaxf(y, __shfl_xor(y, off, 64));
            if (lane == 0) out[OUT1 + (b * 128 + o) * S_ + s] = y;
        }
    }
}

extern "C" void kernel_launch(void* const* d_in, const int* in_sizes, int n_in,
                              void* d_out, int out_size, void* d_ws, size_t ws_size,
                              hipStream_t stream) {
    const float* xyz  = (const float*)d_in[0];
    const float* pts  = (const float*)d_in[1];
    const int*   seed = (const int*)d_in[2];
    const float* w0 = (const float*)d_in[3];
    const float* b0 = (const float*)d_in[4];
    const float* g0 = (const float*)d_in[5];
    const float* be0 = (const float*)d_in[6];
    const float* m0 = (const float*)d_in[7];
    const float* v0 = (const float*)d_in[8];
    const float* w1 = (const float*)d_in[9];
    const float* b1 = (const float*)d_in[10];
    const float* g1 = (const float*)d_in[11];
    const float* be1 = (const float*)d_in[12];
    const float* m1 = (const float*)d_in[13];
    const float* v1 = (const float*)d_in[14];
    const float* w2 = (const float*)d_in[15];
    const float* b2 = (const float*)d_in[16];
    const float* g2 = (const float*)d_in[17];
    const float* be2 = (const float*)d_in[18];
    const float* m2 = (const float*)d_in[19];
    const float* v2 = (const float*)d_in[20];
    float* out = (float*)d_out;
    (void)d_ws; (void)ws_size;   // workspace intentionally unused

    fps_kernel<<<dim3(B_), dim3(256), 0, stream>>>(xyz, out);
    gather_kernel<<<dim3(8192 / 256), dim3(256), 0, stream>>>(xyz, seed, out);
    ballquery_kernel<<<dim3(2048), dim3(256), 0, stream>>>(xyz, out);
    mlp_kernel<<<dim3(8192), dim3(256), 0, stream>>>(xyz, pts,
        w0, b0, g0, be0, m0, v0,
        w1, b1, g1, be1, m1, v1,
        w2, b2, g2, be2, m2, v2,
        out);
}

// Round 7
// 1649.959 us; speedup vs baseline: 1.5862x; 1.0076x over previous
//
#include <hip/hip_runtime.h>

#define B_ 8
#define N_ 8192
#define S_ 1024
#define NS_ 64

typedef float v2f __attribute__((ext_vector_type(2)));

// out layout (floats) — also used as staging (fully rewritten every launch)
#define OUT0 0                 // new_xyz (B,3,1024)
#define OUT1 24576             // new_points (B,128,1024); rows 0..63 of each
                               //   column hold gi int-bits between kernels 3&4
#define OUT2 1073152           // new_seed (B,1024); holds fps int-bits between
                               //   kernels 1&2

// ---------------------------------------------------------------------------
// DPP 64-lane reductions (row_shr 1/2/4/8, row_bcast 15/31; result lane 63).
// ---------------------------------------------------------------------------
template <int CTRL>
static __device__ __forceinline__ float dpp_max_step(float v) {
    int o = __builtin_amdgcn_update_dpp(__float_as_int(v), __float_as_int(v),
                                        CTRL, 0xf, 0xf, false);
    return fmaxf(v, __int_as_float(o));
}
static __device__ __forceinline__ float wave_max_f32(float v) {
    v = dpp_max_step<0x111>(v);
    v = dpp_max_step<0x112>(v);
    v = dpp_max_step<0x114>(v);
    v = dpp_max_step<0x118>(v);
    v = dpp_max_step<0x142>(v);
    v = dpp_max_step<0x143>(v);
    return __int_as_float(__builtin_amdgcn_readlane(__float_as_int(v), 63));
}
template <int CTRL>
static __device__ __forceinline__ unsigned dpp_umin_step(unsigned v) {
    unsigned o = (unsigned)__builtin_amdgcn_update_dpp((int)v, (int)v,
                                                       CTRL, 0xf, 0xf, false);
    return v < o ? v : o;
}
static __device__ __forceinline__ unsigned wave_min_u32(unsigned v) {
    v = dpp_umin_step<0x111>(v);
    v = dpp_umin_step<0x112>(v);
    v = dpp_umin_step<0x114>(v);
    v = dpp_umin_step<0x118>(v);
    v = dpp_umin_step<0x142>(v);
    v = dpp_umin_step<0x143>(v);
    return (unsigned)__builtin_amdgcn_readlane((int)v, 63);
}

// ---------------------------------------------------------------------------
// Kernel 1: farthest point sampling. One block/batch, 512 threads (8 waves),
// 16 pts/thread as 8 float2 (v_pk_* — IEEE-identical to scalar, so argmax
// matches numpy bit-exactly). ONE barrier per step:
//   dist update -> DPP wave value-max -> rescan (16 cmp) for local min idx
//   -> DPP wave idx-min -> lane0 atomicMax(u64 pairs[(step+1)&1]) with
//   packed (step+1)<<45 | dist_bits<<13 | (8191-idx)  [step tag monotone =>
//   stale entries always lose => NO reset needed] -> barrier -> broadcast
//   read -> coord fetch. Double-buffered pairs[]: reads of a buffer finish
//   before the barrier that precedes its next writers => provably race-free.
// ---------------------------------------------------------------------------
#define FPS_T 512
#define FPS_J 8     // float2 per thread (16 points)

__global__ __launch_bounds__(FPS_T, 1) void fps_kernel(const float* __restrict__ xyz,
                                                       float* out) {
    const int b = blockIdx.x;
    const int t = threadIdx.x;          // 0..511
    const int lane = t & 63;
    const float* X = xyz + b * 3 * N_;

    // pair j components: n = t + 1024*j (x), n + 512 (y); bit 2j -> n, 2j+1 -> n+512
    v2f px2[FPS_J], py2[FPS_J], pz2[FPS_J], dist2[FPS_J];
#pragma unroll
    for (int j = 0; j < FPS_J; ++j) {
        int n = t + 1024 * j;
        px2[j] = (v2f){X[n], X[n + 512]};
        py2[j] = (v2f){X[N_ + n], X[N_ + n + 512]};
        pz2[j] = (v2f){X[2 * N_ + n], X[2 * N_ + n + 512]};
        dist2[j] = (v2f){1e10f, 1e10f};
    }

    __shared__ unsigned long long pairs[2];
    if (t == 0) { pairs[0] = 0ull; pairs[1] = 0ull; }
    __syncthreads();

    float* oseed = out + OUT2 + b * S_;

    int ci = 0;
    float c0 = X[0], c1 = X[N_], c2 = X[2 * N_];

    for (int step = 0; step < S_; ++step) {
        if (t == 0) oseed[step] = __int_as_float(ci);

        // packed dist update + value-only max
        v2f mv = (v2f){-1.0f, -1.0f};
        {
#pragma clang fp contract(off)
            v2f c0v = (v2f){c0, c0};
            v2f c1v = (v2f){c1, c1};
            v2f c2v = (v2f){c2, c2};
#pragma unroll
            for (int j = 0; j < FPS_J; ++j) {
                v2f e0 = px2[j] - c0v;
                v2f e1 = py2[j] - c1v;
                v2f e2 = pz2[j] - c2v;
                v2f q0 = e0 * e0;
                v2f q1 = e1 * e1;
                v2f q2 = e2 * e2;
                v2f d  = (q0 + q1) + q2;
                v2f dm = __builtin_elementwise_min(dist2[j], d);
                dist2[j] = dm;
                mv = __builtin_elementwise_max(mv, dm);
            }
        }
        float m = fmaxf(mv.x, mv.y);

        // wave value max
        float wmax = wave_max_f32(m);

        // rescan vs wave max -> this thread's lowest matching point index
        unsigned mask = 0u;
#pragma unroll
        for (int j = 0; j < FPS_J; ++j) {
            if (dist2[j].x == wmax) mask |= (1u << (2 * j));
            if (dist2[j].y == wmax) mask |= (1u << (2 * j + 1));
        }
        unsigned cand = 0xffffffffu;
        if (mask) {
            int bit = __ffs(mask) - 1;
            cand = (unsigned)(t + (bit << 9));   // = point index n
        }
        unsigned widx = wave_min_u32(cand);      // wave's winning point index

        if (lane == 0) {
            unsigned long long pv =
                ((unsigned long long)(step + 1) << 45) |
                ((unsigned long long)__float_as_uint(wmax) << 13) |
                (unsigned long long)(8191u - widx);
            atomicMax(&pairs[(step + 1) & 1], pv);
        }
        __syncthreads();   // the ONE barrier

        unsigned long long p = pairs[(step + 1) & 1];
        ci = 8191 - (int)(p & 0x1fffull);
        int cu = __builtin_amdgcn_readfirstlane(ci);
        c0 = X[cu];
        c1 = X[N_ + cu];
        c2 = X[2 * N_ + cu];
    }
}

// ---------------------------------------------------------------------------
// Kernel 2: read fps int-bits from OUT2, gather centroid coords -> OUT0,
// overwrite OUT2 with the gathered seed value (same-thread read-then-write).
// ---------------------------------------------------------------------------
__global__ __launch_bounds__(256) void gather_kernel(const float* __restrict__ xyz,
                                                     const int* __restrict__ seed,
                                                     float* out) {
    int t = blockIdx.x * 256 + threadIdx.x;   // 8192
    int b = t >> 10, s = t & 1023;
    int idx = __float_as_int(out[OUT2 + t]) & 8191;
    const float* X = xyz + b * 3 * N_;
    float x = X[idx], y = X[N_ + idx], z = X[2 * N_ + idx];
    out[OUT0 + (b * 3 + 0) * S_ + s] = x;
    out[OUT0 + (b * 3 + 1) * S_ + s] = y;
    out[OUT0 + (b * 3 + 2) * S_ + s] = z;
    out[OUT2 + t] = (float)seed[b * N_ + idx];
}

// ---------------------------------------------------------------------------
// Kernel 3: ball query. One wave per centroid; ballot-compaction collects the
// 64 lowest-index in-radius points; pad with first. |c|^2 and |x|^2
// recomputed inline in the reference op order; result indices stored as
// int-bits in rows 0..63 of this centroid's own OUT1 column.
// ---------------------------------------------------------------------------
__global__ __launch_bounds__(256) void ballquery_kernel(const float* __restrict__ xyz,
                                                        float* out) {
    int wid = threadIdx.x >> 6, lane = threadIdx.x & 63;
    int sg = blockIdx.x * 4 + wid;            // 0..8191 centroid id
    int b = sg >> 10, s = sg & 1023;
    const float* X = xyz + b * 3 * N_;
    float c0 = out[OUT0 + (b * 3 + 0) * S_ + s];
    float c1 = out[OUT0 + (b * 3 + 1) * S_ + s];
    float c2 = out[OUT0 + (b * 3 + 2) * S_ + s];
    float ss;
    {
#pragma clang fp contract(off)
        ss = (c0 * c0 + c1 * c1) + c2 * c2;
    }
    float* G = out + OUT1 + (b * 128) * S_ + s;   // column s, rows 0..63, stride S_

    int cnt = 0, first = 0;
    for (int base = 0; base < N_ && cnt < NS_; base += 64) {
        int n = base + lane;
        float x = X[n], y = X[N_ + n], z = X[2 * N_ + n];
        float d;
        {
#pragma clang fp contract(off)
            float ds = (x * x + y * y) + z * z;
            float dot = (x * c0 + y * c1) + z * c2;
            d = ((-2.0f * dot) + ss) + ds;
        }
        bool inr = (d <= 0.04f);
        unsigned long long mask = __ballot(inr);
        if (mask) {
            if (cnt == 0) first = base + __ffsll((unsigned long long)mask) - 1;
            int pos = cnt + (int)__popcll(mask & ((1ull << lane) - 1ull));
            if (inr && pos < NS_) G[pos * S_] = __int_as_float(n);
            cnt += (int)__popcll(mask);
        }
    }
    if (lane >= cnt && lane < NS_) G[lane * S_] = __int_as_float(first);
}

// ---------------------------------------------------------------------------
// Kernel 4: fused gather + 3-layer pointwise MLP (+BN+ReLU) + max over K.
// One block (256 thr) per centroid. k = lane (64 rows), wave wq owns an
// o-slice. Reads gi int-bits from its own OUT1 column, then overwrites that
// column with the final features (read happens before first barrier; writes
// at the end — same block only, race-free).
// ---------------------------------------------------------------------------
__global__ __launch_bounds__(256) void mlp_kernel(
    const float* __restrict__ xyz, const float* __restrict__ pts,
    const float* __restrict__ w0, const float* __restrict__ b0,
    const float* __restrict__ g0, const float* __restrict__ be0,
    const float* __restrict__ m0, const float* __restrict__ v0,
    const float* __restrict__ w1, const float* __restrict__ b1,
    const float* __restrict__ g1, const float* __restrict__ be1,
    const float* __restrict__ m1, const float* __restrict__ v1,
    const float* __restrict__ w2, const float* __restrict__ b2,
    const float* __restrict__ g2, const float* __restrict__ be2,
    const float* __restrict__ m2, const float* __restrict__ v2,
    float* out) {
    const int sg = blockIdx.x;
    const int b = sg >> 10, s = sg & 1023;
    const int t = threadIdx.x;
    const int lane = t & 63;
    const int wq = __builtin_amdgcn_readfirstlane(t >> 6);

    __shared__ float f0[64 * 9];
    __shared__ float bufA[64 * 65];
    __shared__ float bufB[64 * 65];

    if (t < 64) {
        int gidx = __float_as_int(out[OUT1 + (b * 128 + t) * S_ + s]) & 8191;
        const float* X = xyz + b * 3 * N_;
        const float* P = pts + b * 3 * N_;
        float cx = out[OUT0 + (b * 3 + 0) * S_ + s];
        float cy = out[OUT0 + (b * 3 + 1) * S_ + s];
        float cz = out[OUT0 + (b * 3 + 2) * S_ + s];
        f0[t * 9 + 0] = X[gidx] - cx;
        f0[t * 9 + 1] = X[N_ + gidx] - cy;
        f0[t * 9 + 2] = X[2 * N_ + gidx] - cz;
        f0[t * 9 + 3] = P[gidx];
        f0[t * 9 + 4] = P[N_ + gidx];
        f0[t * 9 + 5] = P[2 * N_ + gidx];
    }
    __syncthreads();

    // layer 0: 6 -> 64
    {
        float in[6];
#pragma unroll
        for (int c = 0; c < 6; ++c) in[c] = f0[lane * 9 + c];
#pragma unroll 1
        for (int i = 0; i < 16; ++i) {
            int o = wq * 16 + i;
            float acc = 0.0f;
#pragma unroll
            for (int c = 0; c < 6; ++c) acc = fmaf(in[c], w0[o * 6 + c], acc);
            float sc = g0[o] / sqrtf(v0[o] + 1e-5f);
            float y = (acc + b0[o] - m0[o]) * sc + be0[o];
            bufA[lane * 65 + o] = fmaxf(y, 0.0f);
        }
    }
    __syncthreads();

    // layer 1: 64 -> 64
    {
        float r[64];
#pragma unroll
        for (int c = 0; c < 64; ++c) r[c] = bufA[lane * 65 + c];
#pragma unroll 1
        for (int i = 0; i < 16; ++i) {
            int o = wq * 16 + i;
            float acc = 0.0f;
#pragma unroll
            for (int c = 0; c < 64; ++c) acc = fmaf(r[c], w1[o * 64 + c], acc);
            float sc = g1[o] / sqrtf(v1[o] + 1e-5f);
            float y = (acc + b1[o] - m1[o]) * sc + be1[o];
            bufB[lane * 65 + o] = fmaxf(y, 0.0f);
        }
    }
    __syncthreads();

    // layer 2: 64 -> 128, fused BN+ReLU+max over k (k = lane -> wave reduce)
    {
        float r[64];
#pragma unroll
        for (int c = 0; c < 64; ++c) r[c] = bufB[lane * 65 + c];
#pragma unroll 1
        for (int i = 0; i < 32; ++i) {
            int o = wq * 32 + i;
            float acc = 0.0f;
#pragma unroll
            for (int c = 0; c < 64; ++c) acc = fmaf(r[c], w2[o * 64 + c], acc);
            float sc = g2[o] / sqrtf(v2[o] + 1e-5f);
            float y = (acc + b2[o] - m2[o]) * sc + be2[o];
            y = fmaxf(y, 0.0f);
#pragma unroll
            for (int off = 1; off < 64; off <<= 1)
                y = fmaxf(y, __shfl_xor(y, off, 64));
            if (lane == 0) out[OUT1 + (b * 128 + o) * S_ + s] = y;
        }
    }
}

extern "C" void kernel_launch(void* const* d_in, const int* in_sizes, int n_in,
                              void* d_out, int out_size, void* d_ws, size_t ws_size,
                              hipStream_t stream) {
    const float* xyz  = (const float*)d_in[0];
    const float* pts  = (const float*)d_in[1];
    const int*   seed = (const int*)d_in[2];
    const float* w0 = (const float*)d_in[3];
    const float* b0 = (const float*)d_in[4];
    const float* g0 = (const float*)d_in[5];
    const float* be0 = (const float*)d_in[6];
    const float* m0 = (const float*)d_in[7];
    const float* v0 = (const float*)d_in[8];
    const float* w1 = (const float*)d_in[9];
    const float* b1 = (const float*)d_in[10];
    const float* g1 = (const float*)d_in[11];
    const float* be1 = (const float*)d_in[12];
    const float* m1 = (const float*)d_in[13];
    const float* v1 = (const float*)d_in[14];
    const float* w2 = (const float*)d_in[15];
    const float* b2 = (const float*)d_in[16];
    const float* g2 = (const float*)d_in[17];
    const float* be2 = (const float*)d_in[18];
    const float* m2 = (const float*)d_in[19];
    const float* v2 = (const float*)d_in[20];
    float* out = (float*)d_out;
    (void)d_ws; (void)ws_size;   // workspace intentionally unused

    fps_kernel<<<dim3(B_), dim3(FPS_T), 0, stream>>>(xyz, out);
    gather_kernel<<<dim3(8192 / 256), dim3(256), 0, stream>>>(xyz, seed, out);
    ballquery_kernel<<<dim3(2048), dim3(256), 0, stream>>>(xyz, out);
    mlp_kernel<<<dim3(8192), dim3(256), 0, stream>>>(xyz, pts,
        w0, b0, g0, be0, m0, v0,
        w1, b1, g1, be1, m1, v1,
        w2, b2, g2, be2, m2, v2,
        out);
}